// Round 5
// baseline (249.747 us; speedup 1.0000x reference)
//
#include <hip/hip_runtime.h>

#define BATCH 128
#define M 259
#define D 512
#define T 256
#define NM (BATCH * M)          // 33152
#define OUTHALF (BATCH * T * D)

typedef __bf16 bf16;
typedef __bf16 bf16x4 __attribute__((ext_vector_type(4)));
typedef __bf16 bf16x8 __attribute__((ext_vector_type(8)));
typedef float f32x4 __attribute__((ext_vector_type(4)));

// ws float layout: wcol[NM] | wrow[NM] | (unused NM) | probe-scratch[NM]

__global__ void k_zero(float4* __restrict__ ws4) {
    int i = blockIdx.x * 256 + threadIdx.x;
    if (i < NM) ws4[i] = make_float4(0.f, 0.f, 0.f, 0.f);  // 4*NM floats
}

#define BT 144
#define BK 64

// MODE: 0 = real. 10 = probe full body. 11 = probe stage-side only (no MFMA).
// 12 = probe LDS+MFMA side only (no global loads). Probes atomic into ws[3*NM..).
template <int MODE>
__launch_bounds__(576, 5)
__global__ void k_pairs_t(const float* __restrict__ x1, const float* __restrict__ x2,
                          float* __restrict__ ws) {
    constexpr bool PROBE     = (MODE != 0);
    constexpr bool SKIP_MFMA = (MODE == 11);
    constexpr bool SKIP_LOAD = (MODE == 12);

    __shared__ __align__(16) bf16 As[BT * BK];
    __shared__ __align__(16) bf16 Bs[BT * BK];
    __shared__ float na_s[BT];
    __shared__ float nb_s[BT];

    int bid;
    if (!PROBE) {
        int s = blockIdx.x;                 // 512 = 8 * 64, bijective XCD swizzle
        bid = (s & 7) * 64 + (s >> 3);
    } else {
        bid = (blockIdx.x * 9 + 1) & 511;   // 64-sample of the 512-block space
    }
    int b  = bid >> 2;
    int ti = (bid >> 1) & 1;
    int tj = bid & 1;
    int i0 = ti * BT, j0 = tj * BT;

    int t    = threadIdx.x;
    int lane = t & 63;
    int w    = t / 64;
    int wm   = w / 3, wn = w % 3;           // 3x3 wave grid, 48x48 per wave
    int iw   = i0 + wm * 48;
    int jw   = j0 + wn * 48;

    const float* Ab = x1 + (size_t)b * M * D;
    const float* Bb = x2 + (size_t)b * M * D;

    const float* pa[4];
    const float* pb[4];
    int c4 = (t & 15) * 4;
#pragma unroll
    for (int p = 0; p < 4; ++p) {
        int row = p * 36 + (t >> 4);        // [0,144)
        int ra = min(i0 + row, M - 1);
        int rb = min(j0 + row, M - 1);
        pa[p] = Ab + (size_t)ra * D + c4;
        pb[p] = Bb + (size_t)rb * D + c4;
    }
    int wslot   = (t & 15) >> 1;
    int wwithin = (t & 1) * 4;
    int wr_off[4];
#pragma unroll
    for (int p = 0; p < 4; ++p) {
        int row = p * 36 + (t >> 4);
        wr_off[p] = row * BK + ((wslot ^ (row & 7)) << 3) + wwithin;
    }

    int a_off[3][2], b_off[3][2];
#pragma unroll
    for (int fm = 0; fm < 3; ++fm) {
        int rowa = wm * 48 + fm * 16 + (lane & 15);
        int rowb = wn * 48 + fm * 16 + (lane & 15);
#pragma unroll
        for (int kk = 0; kk < 2; ++kk) {
            int slot = kk * 4 + (lane >> 4);
            a_off[fm][kk] = rowa * BK + ((slot ^ (rowa & 7)) << 3);
            b_off[fm][kk] = rowb * BK + ((slot ^ (rowb & 7)) << 3);
        }
    }

    f32x4 acc[3][3];
#pragma unroll
    for (int fm = 0; fm < 3; ++fm)
#pragma unroll
        for (int fn = 0; fn < 3; ++fn) acc[fm][fn] = (f32x4)0.f;

    float sa[4], sb[4];
#pragma unroll
    for (int p = 0; p < 4; ++p) { sa[p] = 0.f; sb[p] = 0.f; }

    for (int k0 = 0; k0 < D; k0 += BK) {
        float4 va[4], vb[4];
#pragma unroll
        for (int p = 0; p < 4; ++p) {
            if (!SKIP_LOAD) {
                va[p] = *(const float4*)(pa[p] + k0);
                vb[p] = *(const float4*)(pb[p] + k0);
            } else {
                va[p] = make_float4(0.f, 0.f, 0.f, 0.f);
                vb[p] = make_float4(0.f, 0.f, 0.f, 0.f);
            }
        }
#pragma unroll
        for (int p = 0; p < 4; ++p) {
            sa[p] += va[p].x * va[p].x + va[p].y * va[p].y
                   + va[p].z * va[p].z + va[p].w * va[p].w;
            sb[p] += vb[p].x * vb[p].x + vb[p].y * vb[p].y
                   + vb[p].z * vb[p].z + vb[p].w * vb[p].w;
        }
        __syncthreads();
#pragma unroll
        for (int p = 0; p < 4; ++p) {
            bf16x4 ca = { (bf16)va[p].x, (bf16)va[p].y, (bf16)va[p].z, (bf16)va[p].w };
            bf16x4 cb = { (bf16)vb[p].x, (bf16)vb[p].y, (bf16)vb[p].z, (bf16)vb[p].w };
            *(bf16x4*)&As[wr_off[p]] = ca;
            *(bf16x4*)&Bs[wr_off[p]] = cb;
        }
        __syncthreads();
        if (!SKIP_MFMA) {
#pragma unroll
            for (int kk = 0; kk < 2; ++kk) {
                bf16x8 af[3], bfr[3];
#pragma unroll
                for (int fm = 0; fm < 3; ++fm) af[fm]  = *(const bf16x8*)&As[a_off[fm][kk]];
#pragma unroll
                for (int fn = 0; fn < 3; ++fn) bfr[fn] = *(const bf16x8*)&Bs[b_off[fn][kk]];
#pragma unroll
                for (int fm = 0; fm < 3; ++fm)
#pragma unroll
                    for (int fn = 0; fn < 3; ++fn)
                        acc[fm][fn] = __builtin_amdgcn_mfma_f32_16x16x32_bf16(
                            af[fm], bfr[fn], acc[fm][fn], 0, 0, 0);
            }
        }
    }

#pragma unroll
    for (int p = 0; p < 4; ++p) {
        float v1 = sa[p], v2 = sb[p];
        v1 += __shfl_xor(v1, 1); v1 += __shfl_xor(v1, 2);
        v1 += __shfl_xor(v1, 4); v1 += __shfl_xor(v1, 8);
        v2 += __shfl_xor(v2, 1); v2 += __shfl_xor(v2, 2);
        v2 += __shfl_xor(v2, 4); v2 += __shfl_xor(v2, 8);
        if ((t & 15) == 0) {
            na_s[p * 36 + (t >> 4)] = v1;
            nb_s[p * 36 + (t >> 4)] = v2;
        }
    }
    __syncthreads();

    float* wcol = ws + (PROBE ? 3 * NM : 0);
    float* wrow = ws + (PROBE ? 3 * NM : NM);
    int b_off_w = b * M;

    if (SKIP_MFMA) {
        float tok = (float)As[t] + (float)Bs[t] + na_s[t % BT] + nb_s[t % BT];
        atomicAdd(&wcol[b_off_w + (t % M)], tok);   // keep-alive commit
        return;
    }

    float na_[3][4], nb_[3];
#pragma unroll
    for (int fm = 0; fm < 3; ++fm)
#pragma unroll
        for (int r = 0; r < 4; ++r)
            na_[fm][r] = na_s[wm * 48 + fm * 16 + (lane >> 4) * 4 + r];
#pragma unroll
    for (int fn = 0; fn < 3; ++fn)
        nb_[fn] = nb_s[wn * 48 + fn * 16 + (lane & 15)];

    float rs[3][4];
    float cs[3];
#pragma unroll
    for (int fm = 0; fm < 3; ++fm)
#pragma unroll
        for (int r = 0; r < 4; ++r) rs[fm][r] = 0.f;
#pragma unroll
    for (int fn = 0; fn < 3; ++fn) cs[fn] = 0.f;

#pragma unroll
    for (int fm = 0; fm < 3; ++fm) {
#pragma unroll
        for (int fn = 0; fn < 3; ++fn) {
#pragma unroll
            for (int r = 0; r < 4; ++r) {
                int i = iw + fm * 16 + (lane >> 4) * 4 + r;
                int j = jw + fn * 16 + (lane & 15);
                float av = 0.f;
                if (i < M && j < M) {
                    float sq   = na_[fm][r] + nb_[fn] - 2.f * acc[fm][fn][r];
                    float dist = sqrtf(fmaxf(sq, 0.f));
                    av = 1.f / (1.f + dist);
                }
                rs[fm][r] += av;
                cs[fn]    += av;
            }
        }
    }

#pragma unroll
    for (int fm = 0; fm < 3; ++fm)
#pragma unroll
        for (int r = 0; r < 4; ++r) {
            float v = rs[fm][r];
            v += __shfl_xor(v, 1); v += __shfl_xor(v, 2);
            v += __shfl_xor(v, 4); v += __shfl_xor(v, 8);
            int i = iw + fm * 16 + (lane >> 4) * 4 + r;
            if ((lane & 15) == 0 && i < M) atomicAdd(&wrow[b_off_w + i], v);
        }
#pragma unroll
    for (int fn = 0; fn < 3; ++fn) {
        float v = cs[fn];
        v += __shfl_xor(v, 16); v += __shfl_xor(v, 32);
        int j = jw + fn * 16 + (lane & 15);
        if ((lane >> 4) == 0 && j < M) atomicAdd(&wcol[b_off_w + j], v);
    }
}

__global__ void k_out(const float* __restrict__ x1, const float* __restrict__ x2,
                      const float* __restrict__ ws, float* __restrict__ out) {
    int bid   = blockIdx.x;
    int which = bid & 1;
    int tc    = (bid >> 1) & 7;
    int b     = bid >> 4;
    int d4    = threadIdx.x << 2;
    const float* src  = which ? x2 : x1;
    const float* wgt  = ws + (which ? NM : 0) + b * M;
    const float* rows = src + (size_t)b * M * D + d4;
    float* o = out + (size_t)which * OUTHALF + ((size_t)b * T + tc * 32) * D + d4;
    int t0 = tc * 32;
    float4 v0 = *(const float4*)(rows + (size_t)(t0 + 0) * D);
    float4 v1 = *(const float4*)(rows + (size_t)(t0 + 1) * D);
    float4 v2 = *(const float4*)(rows + (size_t)(t0 + 2) * D);
    float s0 = wgt[t0 + 0], s1 = wgt[t0 + 1], s2 = wgt[t0 + 2];
#pragma unroll 4
    for (int tt = 0; tt < 32; ++tt) {
        float4 v3 = *(const float4*)(rows + (size_t)(t0 + tt + 3) * D);
        float s3  = wgt[t0 + tt + 3];
        float4 r;
        r.x = s0 * v0.x + s1 * v1.x + s2 * v2.x + s3 * v3.x;
        r.y = s0 * v0.y + s1 * v1.y + s2 * v2.y + s3 * v3.y;
        r.z = s0 * v0.z + s1 * v1.z + s2 * v2.z + s3 * v3.z;
        r.w = s0 * v0.w + s1 * v1.w + s2 * v2.w + s3 * v3.w;
        *(float4*)(o + (size_t)tt * D) = r;
        v0 = v1; v1 = v2; v2 = v3;
        s0 = s1; s1 = s2; s2 = s3;
    }
}

extern "C" void kernel_launch(void* const* d_in, const int* in_sizes, int n_in,
                              void* d_out, int out_size, void* d_ws, size_t ws_size,
                              hipStream_t stream) {
    const float* x1 = (const float*)d_in[0];
    const float* x2 = (const float*)d_in[1];
    float* out = (float*)d_out;
    float* ws  = (float*)d_ws;

    k_zero<<<(NM + 255) / 256, 256, 0, stream>>>((float4*)ws);
    k_pairs_t<0><<<512, 576, 0, stream>>>(x1, x2, ws);    // main
    k_out<<<BATCH * 16, 128, 0, stream>>>(x1, x2, ws, out);
    // ablation probes (1/8 grid, scratch-region atomics, timing-only)
    k_pairs_t<10><<<64, 576, 0, stream>>>(x1, x2, ws);    // P10 full body
    k_pairs_t<11><<<64, 576, 0, stream>>>(x1, x2, ws);    // P11 stage side only
    k_pairs_t<12><<<64, 576, 0, stream>>>(x1, x2, ws);    // P12 LDS+MFMA side only
}

// Round 6
// 117.286 us; speedup vs baseline: 2.1294x; 2.1294x over previous
//
#include <hip/hip_runtime.h>

#define BATCH 128
#define M 259
#define D 512
#define T 256
#define NM (BATCH * M)          // 33152
#define OUTHALF (BATCH * T * D)

typedef __bf16 bf16;
typedef __bf16 bf16x4 __attribute__((ext_vector_type(4)));
typedef __bf16 bf16x8 __attribute__((ext_vector_type(8)));
typedef float f32x4 __attribute__((ext_vector_type(4)));

// ws float layout: na[NM] | nb[NM] | wcol[NM] | wrow[NM]

// ---------------- Kernel 1: norms + zero accumulators ----------------
__global__ void k_norms(const float* __restrict__ x1, const float* __restrict__ x2,
                        float* __restrict__ ws) {
    int wave = blockIdx.x * 4 + (threadIdx.x >> 6);
    int lane = threadIdx.x & 63;
    if (wave >= NM) return;
    const float4* p1 = (const float4*)(x1 + (size_t)wave * D);
    const float4* p2 = (const float4*)(x2 + (size_t)wave * D);
    float s1 = 0.f, s2 = 0.f;
#pragma unroll
    for (int q = 0; q < 2; ++q) {
        float4 v = p1[lane + q * 64];
        s1 += v.x * v.x + v.y * v.y + v.z * v.z + v.w * v.w;
        float4 w = p2[lane + q * 64];
        s2 += w.x * w.x + w.y * w.y + w.z * w.z + w.w * w.w;
    }
#pragma unroll
    for (int off = 32; off > 0; off >>= 1) {
        s1 += __shfl_xor(s1, off);
        s2 += __shfl_xor(s2, off);
    }
    if (lane == 0) {
        ws[wave]          = s1;
        ws[NM + wave]     = s2;
        ws[2 * NM + wave] = 0.f;  // wcol accumulator
        ws[3 * NM + wave] = 0.f;  // wrow accumulator
    }
}

// ---------------- Kernel 2: bf16 MFMA pairwise, double-buffered LDS --------
#define BT 96
#define BK 64
#define NTL 3   // 3*96 = 288 >= 259

__launch_bounds__(256)
__global__ void k_pairs(const float* __restrict__ x1, const float* __restrict__ x2,
                        float* __restrict__ ws) {
    // double-buffered bf16 tiles: 2 * (96*64*2B) * 2 matrices = 48 KB -> 3 blk/CU
    __shared__ __align__(16) bf16 As[2][BT * BK];
    __shared__ __align__(16) bf16 Bs[2][BT * BK];

    // XCD-aware bijective swizzle: 1152 blocks = 8 * 144
    int s   = blockIdx.x;
    int bid = (s & 7) * 144 + (s >> 3);
    int b   = bid / 9;
    int ti  = (bid % 9) / 3;
    int tj  = bid % 3;
    int i0  = ti * BT, j0 = tj * BT;

    int t    = threadIdx.x;
    int lane = t & 63;
    int w    = t >> 6;
    int wm   = w >> 1, wn = w & 1;
    int iw   = i0 + wm * 48;
    int jw   = j0 + wn * 48;

    const float* Ab = x1 + (size_t)b * M * D;
    const float* Bb = x2 + (size_t)b * M * D;

    // staging: 6 passes of 16 rows x 64 cols per matrix, 1 float4/thread/pass
    const float* pa[6];
    const float* pb[6];
    int c4 = (t & 15) * 4;
#pragma unroll
    for (int p = 0; p < 6; ++p) {
        int ra = min(i0 + p * 16 + (t >> 4), M - 1);
        int rb = min(j0 + p * 16 + (t >> 4), M - 1);
        pa[p] = Ab + (size_t)ra * D + c4;
        pb[p] = Bb + (size_t)rb * D + c4;
    }
    int wslot   = (t & 15) >> 1;
    int wwithin = (t & 1) * 4;
    int wr_off[6];
#pragma unroll
    for (int p = 0; p < 6; ++p) {
        int row = p * 16 + (t >> 4);
        wr_off[p] = row * BK + ((wslot ^ (row & 7)) << 3) + wwithin;
    }

    // fragment read offsets (element units), swizzle-matched
    int a_off[3][2], b_off[3][2];
#pragma unroll
    for (int fm = 0; fm < 3; ++fm) {
        int rowa = wm * 48 + fm * 16 + (lane & 15);
        int rowb = wn * 48 + fm * 16 + (lane & 15);
#pragma unroll
        for (int kk = 0; kk < 2; ++kk) {
            int slot = kk * 4 + (lane >> 4);
            a_off[fm][kk] = rowa * BK + ((slot ^ (rowa & 7)) << 3);
            b_off[fm][kk] = rowb * BK + ((slot ^ (rowb & 7)) << 3);
        }
    }

    f32x4 acc[3][3];
#pragma unroll
    for (int fm = 0; fm < 3; ++fm)
#pragma unroll
        for (int fn = 0; fn < 3; ++fn) acc[fm][fn] = (f32x4)0.f;

    float4 va[6], vb[6];
    // ---- prologue: tile 0 -> buf0; tile 1 loads in flight
#pragma unroll
    for (int p = 0; p < 6; ++p) {
        va[p] = *(const float4*)(pa[p]);
        vb[p] = *(const float4*)(pb[p]);
    }
#pragma unroll
    for (int p = 0; p < 6; ++p) {
        bf16x4 ca = { (bf16)va[p].x, (bf16)va[p].y, (bf16)va[p].z, (bf16)va[p].w };
        bf16x4 cb = { (bf16)vb[p].x, (bf16)vb[p].y, (bf16)vb[p].z, (bf16)vb[p].w };
        *(bf16x4*)&As[0][wr_off[p]] = ca;
        *(bf16x4*)&Bs[0][wr_off[p]] = cb;
    }
    __syncthreads();
#pragma unroll
    for (int p = 0; p < 6; ++p) {
        va[p] = *(const float4*)(pa[p] + BK);
        vb[p] = *(const float4*)(pb[p] + BK);
    }

    // ---- main loop: one barrier per iter; loads issued AFTER the barrier so
    // they stay in flight across the next iteration's ds_read+MFMA phase.
    for (int k0 = 0; k0 < D; k0 += BK) {
        int cur = (k0 >> 6) & 1;
#pragma unroll
        for (int kk = 0; kk < 2; ++kk) {
            bf16x8 af[3], bfr[3];
#pragma unroll
            for (int fm = 0; fm < 3; ++fm) af[fm]  = *(const bf16x8*)&As[cur][a_off[fm][kk]];
#pragma unroll
            for (int fn = 0; fn < 3; ++fn) bfr[fn] = *(const bf16x8*)&Bs[cur][b_off[fn][kk]];
#pragma unroll
            for (int fm = 0; fm < 3; ++fm)
#pragma unroll
                for (int fn = 0; fn < 3; ++fn)
                    acc[fm][fn] = __builtin_amdgcn_mfma_f32_16x16x32_bf16(
                        af[fm], bfr[fn], acc[fm][fn], 0, 0, 0);
        }
        if (k0 + BK < D) {
            // consume in-flight loads (tile k0+BK) -> write other buffer
#pragma unroll
            for (int p = 0; p < 6; ++p) {
                bf16x4 ca = { (bf16)va[p].x, (bf16)va[p].y, (bf16)va[p].z, (bf16)va[p].w };
                bf16x4 cb = { (bf16)vb[p].x, (bf16)vb[p].y, (bf16)vb[p].z, (bf16)vb[p].w };
                *(bf16x4*)&As[cur ^ 1][wr_off[p]] = ca;
                *(bf16x4*)&Bs[cur ^ 1][wr_off[p]] = cb;
            }
            __syncthreads();
            if (k0 + 2 * BK < D) {
#pragma unroll
                for (int p = 0; p < 6; ++p) {
                    va[p] = *(const float4*)(pa[p] + k0 + 2 * BK);
                    vb[p] = *(const float4*)(pb[p] + k0 + 2 * BK);
                }
            }
        }
    }

    // ---- epilogue: A_ij = 1/(1+dist), masked; row/col partial sums
    int b_off_w = b * M;
    float na_[3][4], nb_[3];
#pragma unroll
    for (int fm = 0; fm < 3; ++fm)
#pragma unroll
        for (int r = 0; r < 4; ++r) {
            int i = iw + fm * 16 + (lane >> 4) * 4 + r;
            na_[fm][r] = (i < M) ? ws[b_off_w + i] : 0.f;
        }
#pragma unroll
    for (int fn = 0; fn < 3; ++fn) {
        int j = jw + fn * 16 + (lane & 15);
        nb_[fn] = (j < M) ? ws[NM + b_off_w + j] : 0.f;
    }

    float rs[3][4];
    float cs[3];
#pragma unroll
    for (int fm = 0; fm < 3; ++fm)
#pragma unroll
        for (int r = 0; r < 4; ++r) rs[fm][r] = 0.f;
#pragma unroll
    for (int fn = 0; fn < 3; ++fn) cs[fn] = 0.f;

#pragma unroll
    for (int fm = 0; fm < 3; ++fm) {
#pragma unroll
        for (int fn = 0; fn < 3; ++fn) {
#pragma unroll
            for (int r = 0; r < 4; ++r) {
                int i = iw + fm * 16 + (lane >> 4) * 4 + r;
                int j = jw + fn * 16 + (lane & 15);
                float av = 0.f;
                if (i < M && j < M) {
                    float sq   = na_[fm][r] + nb_[fn] - 2.f * acc[fm][fn][r];
                    float dist = sqrtf(fmaxf(sq, 0.f));
                    av = 1.f / (1.f + dist);
                }
                rs[fm][r] += av;
                cs[fn]    += av;
            }
        }
    }

#pragma unroll
    for (int fm = 0; fm < 3; ++fm)
#pragma unroll
        for (int r = 0; r < 4; ++r) {
            float v = rs[fm][r];
            v += __shfl_xor(v, 1); v += __shfl_xor(v, 2);
            v += __shfl_xor(v, 4); v += __shfl_xor(v, 8);
            int i = iw + fm * 16 + (lane >> 4) * 4 + r;
            if ((lane & 15) == 0 && i < M) atomicAdd(&ws[3 * NM + b_off_w + i], v);  // wrow
        }
#pragma unroll
    for (int fn = 0; fn < 3; ++fn) {
        float v = cs[fn];
        v += __shfl_xor(v, 16); v += __shfl_xor(v, 32);
        int j = jw + fn * 16 + (lane & 15);
        if ((lane >> 4) == 0 && j < M) atomicAdd(&ws[2 * NM + b_off_w + j], v);      // wcol
    }
}

// ---------------- Kernel 3: sliding-window weighted sum (float4) -----------
__global__ void k_out(const float* __restrict__ x1, const float* __restrict__ x2,
                      const float* __restrict__ ws, float* __restrict__ out) {
    int bid   = blockIdx.x;
    int which = bid & 1;
    int tc    = (bid >> 1) & 7;
    int b     = bid >> 4;
    int d4    = threadIdx.x << 2;
    const float* src  = which ? x2 : x1;
    const float* wgt  = ws + (which ? 3 * NM : 2 * NM) + b * M;
    const float* rows = src + (size_t)b * M * D + d4;
    float* o = out + (size_t)which * OUTHALF + ((size_t)b * T + tc * 32) * D + d4;
    int t0 = tc * 32;
    float4 v0 = *(const float4*)(rows + (size_t)(t0 + 0) * D);
    float4 v1 = *(const float4*)(rows + (size_t)(t0 + 1) * D);
    float4 v2 = *(const float4*)(rows + (size_t)(t0 + 2) * D);
    float s0 = wgt[t0 + 0], s1 = wgt[t0 + 1], s2 = wgt[t0 + 2];
#pragma unroll 4
    for (int tt = 0; tt < 32; ++tt) {
        float4 v3 = *(const float4*)(rows + (size_t)(t0 + tt + 3) * D);
        float s3  = wgt[t0 + tt + 3];
        float4 r;
        r.x = s0 * v0.x + s1 * v1.x + s2 * v2.x + s3 * v3.x;
        r.y = s0 * v0.y + s1 * v1.y + s2 * v2.y + s3 * v3.y;
        r.z = s0 * v0.z + s1 * v1.z + s2 * v2.z + s3 * v3.z;
        r.w = s0 * v0.w + s1 * v1.w + s2 * v2.w + s3 * v3.w;
        *(float4*)(o + (size_t)tt * D) = r;
        v0 = v1; v1 = v2; v2 = v3;
        s0 = s1; s1 = s2; s2 = s3;
    }
}

extern "C" void kernel_launch(void* const* d_in, const int* in_sizes, int n_in,
                              void* d_out, int out_size, void* d_ws, size_t ws_size,
                              hipStream_t stream) {
    const float* x1 = (const float*)d_in[0];
    const float* x2 = (const float*)d_in[1];
    float* out = (float*)d_out;
    float* ws  = (float*)d_ws;

    k_norms<<<NM / 4, 256, 0, stream>>>(x1, x2, ws);              // 8288 blocks
    k_pairs<<<BATCH * NTL * NTL, 256, 0, stream>>>(x1, x2, ws);   // 1152 blocks
    k_out<<<BATCH * 16, 128, 0, stream>>>(x1, x2, ws, out);       // 2048 blocks
}